// Round 10
// baseline (116.786 us; speedup 1.0000x reference)
//
#include <hip/hip_runtime.h>
#include <math.h>

// Gumbel subset (relaxed top-k) — B=2048 rows, N=8192, K=64 softmax steps.
// Multiplicative reformulation: v_i = exp(s0_i - M0), per step:
//   kh += v*rinv; v = v - rinv*v^2; part' = sum(v).
// R10: R9's passing skeleton, but the inner loop is REAL packed fp32 via
// inline-asm VOP3P (v_pk_mul/fma/add_f32, 2 f32/instr). R7/R9 proved the
// compiler scalarizes ext-vector math (busy stuck at 67us == scalar count).
// Asm safety rules learned from R4/R5: NO tied operands, NO neg modifiers —
// every asm is single-instr, pure, early-clobber "=&v" dest disjoint from
// inputs; negation precomputed in C (rn2 = {-rinv,-rinv}).
// Per pair: sq=pk_mul(v,v); kh=pk_fma(v,r2,kh); v=pk_fma(sq,rn2,v);
//           acc=pk_add(acc,v)  -> 2 instr/elem (was 4).

typedef float f2 __attribute__((ext_vector_type(2)));

#define BROWS 2048
#define NCOLS 8192
#define KSTEPS 64

#define THREADS 256
#define EPT (NCOLS / THREADS)  // 32 f32 elements per thread
#define NPK (EPT / 2)          // 16 float2 packs
#define NWAVE (THREADS / 64)   // 4

__global__ __launch_bounds__(THREADS, 4) void gumbel_subset_kernel(
    const float* __restrict__ scores,
    const float* __restrict__ g,
    float* __restrict__ out)
{
    const int row = blockIdx.x;
    const int t = threadIdx.x;
    const float* __restrict__ srow = scores + (size_t)row * NCOLS;
    const float* __restrict__ grow = g + (size_t)row * NCOLS;
    float* __restrict__ orow = out + (size_t)row * NCOLS;

    f2 v[NPK];   // softmax weights (packed pairs)
    f2 kh[NPK];  // khot accumulator

    // ---- load s0 = scores + g (coalesced float4) into packs, local max ----
    f2 mx2 = (f2){-INFINITY, -INFINITY};
#pragma unroll
    for (int c = 0; c < EPT / 4; ++c) {
        const int idx = c * (THREADS * 4) + t * 4;
        const float4 a = *reinterpret_cast<const float4*>(srow + idx);
        const float4 b = *reinterpret_cast<const float4*>(grow + idx);
        const f2 p0 = (f2){a.x + b.x, a.y + b.y};
        const f2 p1 = (f2){a.z + b.z, a.w + b.w};
        v[2 * c + 0] = p0;
        v[2 * c + 1] = p1;
        mx2 = __builtin_elementwise_max(mx2, __builtin_elementwise_max(p0, p1));
    }
    float m = fmaxf(mx2.x, mx2.y);

    __shared__ float red[2][NWAVE]; // double-buffered per-wave partials
    const int wave = t >> 6;
    const int lane = t & 63;

    // ---- block max reduction (once) ----
#pragma unroll
    for (int off = 32; off > 0; off >>= 1)
        m = fmaxf(m, __shfl_xor(m, off, 64));
    if (lane == 0) red[0][wave] = m;
    __syncthreads();
    m = fmaxf(fmaxf(red[0][0], red[0][1]), fmaxf(red[0][2], red[0][3]));
    __syncthreads(); // red[0] is re-written by iteration 0 below

    // ---- v = exp(s0 - M0), kh = 0, initial partial sums ----
    f2 acc0 = (f2){0.0f, 0.0f};
    f2 acc1 = acc0;
#pragma unroll
    for (int p = 0; p < NPK; p += 2) {
        v[p + 0] = (f2){__expf(v[p + 0].x - m), __expf(v[p + 0].y - m)};
        v[p + 1] = (f2){__expf(v[p + 1].x - m), __expf(v[p + 1].y - m)};
        kh[p + 0] = (f2){0.0f, 0.0f};
        kh[p + 1] = (f2){0.0f, 0.0f};
        acc0 += v[p + 0];
        acc1 += v[p + 1];
    }
    float part = (acc0.x + acc0.y) + (acc1.x + acc1.y);

    // ---- K relaxation steps ----
#pragma unroll 2
    for (int it = 0; it < KSTEPS; ++it) {
        float s = part;
#pragma unroll
        for (int off = 32; off > 0; off >>= 1)
            s += __shfl_xor(s, off, 64);

        const int buf = it & 1;
        if (lane == 0) red[buf][wave] = s;
        __syncthreads();
        const float S = (red[buf][0] + red[buf][1]) + (red[buf][2] + red[buf][3]);
        const float rinv = __builtin_amdgcn_rcpf(S);
        const f2 r2 = (f2){rinv, rinv};
        const f2 rn2 = (f2){-rinv, -rinv};

        f2 a0 = (f2){0.0f, 0.0f};
        f2 a1 = a0, a2 = a0, a3 = a0;
#pragma unroll
        for (int p = 0; p < NPK; p += 4) {
            f2 sq0, kn0, vn0, an0;
            asm("v_pk_mul_f32 %0, %1, %1" : "=&v"(sq0) : "v"(v[p + 0]));
            asm("v_pk_fma_f32 %0, %1, %2, %3" : "=&v"(kn0) : "v"(v[p + 0]), "v"(r2), "v"(kh[p + 0]));
            kh[p + 0] = kn0;
            asm("v_pk_fma_f32 %0, %1, %2, %3" : "=&v"(vn0) : "v"(sq0), "v"(rn2), "v"(v[p + 0]));
            v[p + 0] = vn0;
            asm("v_pk_add_f32 %0, %1, %2" : "=&v"(an0) : "v"(a0), "v"(v[p + 0]));
            a0 = an0;

            f2 sq1, kn1, vn1, an1;
            asm("v_pk_mul_f32 %0, %1, %1" : "=&v"(sq1) : "v"(v[p + 1]));
            asm("v_pk_fma_f32 %0, %1, %2, %3" : "=&v"(kn1) : "v"(v[p + 1]), "v"(r2), "v"(kh[p + 1]));
            kh[p + 1] = kn1;
            asm("v_pk_fma_f32 %0, %1, %2, %3" : "=&v"(vn1) : "v"(sq1), "v"(rn2), "v"(v[p + 1]));
            v[p + 1] = vn1;
            asm("v_pk_add_f32 %0, %1, %2" : "=&v"(an1) : "v"(a1), "v"(v[p + 1]));
            a1 = an1;

            f2 sq2, kn2, vn2, an2;
            asm("v_pk_mul_f32 %0, %1, %1" : "=&v"(sq2) : "v"(v[p + 2]));
            asm("v_pk_fma_f32 %0, %1, %2, %3" : "=&v"(kn2) : "v"(v[p + 2]), "v"(r2), "v"(kh[p + 2]));
            kh[p + 2] = kn2;
            asm("v_pk_fma_f32 %0, %1, %2, %3" : "=&v"(vn2) : "v"(sq2), "v"(rn2), "v"(v[p + 2]));
            v[p + 2] = vn2;
            asm("v_pk_add_f32 %0, %1, %2" : "=&v"(an2) : "v"(a2), "v"(v[p + 2]));
            a2 = an2;

            f2 sq3, kn3, vn3, an3;
            asm("v_pk_mul_f32 %0, %1, %1" : "=&v"(sq3) : "v"(v[p + 3]));
            asm("v_pk_fma_f32 %0, %1, %2, %3" : "=&v"(kn3) : "v"(v[p + 3]), "v"(r2), "v"(kh[p + 3]));
            kh[p + 3] = kn3;
            asm("v_pk_fma_f32 %0, %1, %2, %3" : "=&v"(vn3) : "v"(sq3), "v"(rn2), "v"(v[p + 3]));
            v[p + 3] = vn3;
            asm("v_pk_add_f32 %0, %1, %2" : "=&v"(an3) : "v"(a3), "v"(v[p + 3]));
            a3 = an3;
        }
        const f2 aa = (a0 + a1) + (a2 + a3);
        part = aa.x + aa.y;
        // single barrier per iteration: next write targets the other buffer;
        // this buffer is only re-written after the *next* barrier.
    }

    // ---- store khot (coalesced float4) ----
#pragma unroll
    for (int c = 0; c < EPT / 4; ++c) {
        const int idx = c * (THREADS * 4) + t * 4;
        float4 o;
        o.x = kh[2 * c + 0].x;
        o.y = kh[2 * c + 0].y;
        o.z = kh[2 * c + 1].x;
        o.w = kh[2 * c + 1].y;
        *reinterpret_cast<float4*>(orow + idx) = o;
    }
}

extern "C" void kernel_launch(void* const* d_in, const int* in_sizes, int n_in,
                              void* d_out, int out_size, void* d_ws, size_t ws_size,
                              hipStream_t stream) {
    const float* scores = (const float*)d_in[0];
    const float* g = (const float*)d_in[1];
    float* out = (float*)d_out;
    (void)in_sizes; (void)n_in; (void)out_size; (void)d_ws; (void)ws_size;

    gumbel_subset_kernel<<<BROWS, THREADS, 0, stream>>>(scores, g, out);
}

// Round 11
// 103.924 us; speedup vs baseline: 1.1238x; 1.1238x over previous
//
#include <hip/hip_runtime.h>
#include <math.h>

// Gumbel subset (relaxed top-k) — B=2048 rows, N=8192, K=64 softmax steps.
// Multiplicative reformulation: v_i = exp(s0_i - M0), per step:
//   w = v*rinv(S); kh += w; v = fma(-w, v, v); part' = sum(v).
// R11: R7's passing fp16 skeleton (absmax 0.031), inner loop as REAL packed
// fp16 via inline asm (v_pk_mul/fma/add_f16, 2 elems/instr). R9/R10 showed
// pk_f32 is 2-pass on CDNA4 (157.3 TF = scalar SIMD-32 rate) -> no gain;
// fp16 VOP3P packs 2x16b in one 32b lane reg, candidate true dual-rate.
// State halves in fp16 (v+kh = 32 regs) -> fits arch VGPRs, no accvgpr tax.
// Asm style per R10's numerically-proven rules: pure ops, early-clobber
// "=&v" dest, no tied operands, no neg modifiers (rn2/n1 precomputed).
// Per pack: nw = v*(-rinv); kh = nw*(-1)+kh; v = nw*v+v; acc = acc+v.
// Bit-identical arithmetic to R7's update.

typedef _Float16 h2 __attribute__((ext_vector_type(2)));

#define BROWS 2048
#define NCOLS 8192
#define KSTEPS 64

#define THREADS 256
#define EPT (NCOLS / THREADS)  // 32 f32 elements per thread
#define NPAIR (EPT / 2)        // 16 fp16x2 packs
#define NWAVE (THREADS / 64)   // 4

__global__ __launch_bounds__(THREADS, 4) void gumbel_subset_kernel(
    const float* __restrict__ scores,
    const float* __restrict__ g,
    float* __restrict__ out)
{
    const int row = blockIdx.x;
    const int t = threadIdx.x;
    const float* __restrict__ srow = scores + (size_t)row * NCOLS;
    const float* __restrict__ grow = g + (size_t)row * NCOLS;
    float* __restrict__ orow = out + (size_t)row * NCOLS;

    // ---- load s0 = scores + g (coalesced float4), track local max ----
    float s0[EPT];
    float m = -INFINITY;
#pragma unroll
    for (int c = 0; c < EPT / 4; ++c) {
        const int idx = c * (THREADS * 4) + t * 4;
        const float4 a = *reinterpret_cast<const float4*>(srow + idx);
        const float4 b = *reinterpret_cast<const float4*>(grow + idx);
        s0[c * 4 + 0] = a.x + b.x;
        s0[c * 4 + 1] = a.y + b.y;
        s0[c * 4 + 2] = a.z + b.z;
        s0[c * 4 + 3] = a.w + b.w;
        m = fmaxf(m, fmaxf(fmaxf(s0[c * 4 + 0], s0[c * 4 + 1]),
                           fmaxf(s0[c * 4 + 2], s0[c * 4 + 3])));
    }

    __shared__ float red[2][NWAVE]; // double-buffered per-wave partials
    const int wave = t >> 6;
    const int lane = t & 63;

    // ---- block max reduction (once) ----
#pragma unroll
    for (int off = 32; off > 0; off >>= 1)
        m = fmaxf(m, __shfl_xor(m, off, 64));
    if (lane == 0) red[0][wave] = m;
    __syncthreads();
    m = fmaxf(fmaxf(red[0][0], red[0][1]), fmaxf(red[0][2], red[0][3]));
    __syncthreads(); // red[0] is re-written by iteration 0 below

    // ---- v = exp(s0 - M0) packed fp16, kh = 0, initial f32 partial ----
    h2 v[NPAIR];
    h2 kh[NPAIR];
    float part = 0.0f;
#pragma unroll
    for (int p = 0; p < NPAIR; ++p) {
        const float e0 = __expf(s0[2 * p + 0] - m);
        const float e1 = __expf(s0[2 * p + 1] - m);
        v[p] = (h2){(_Float16)e0, (_Float16)e1};
        kh[p] = (h2){(_Float16)0.0f, (_Float16)0.0f};
        part += e0 + e1;
    }

    // ---- K relaxation steps ----
#pragma unroll 2
    for (int it = 0; it < KSTEPS; ++it) {
        float s = part;
#pragma unroll
        for (int off = 32; off > 0; off >>= 1)
            s += __shfl_xor(s, off, 64);

        const int buf = it & 1;
        if (lane == 0) red[buf][wave] = s;
        __syncthreads();
        const float S = (red[buf][0] + red[buf][1]) + (red[buf][2] + red[buf][3]);
        const float rinvf = __builtin_amdgcn_rcpf(S);
        const _Float16 rh = (_Float16)rinvf;
        const h2 rn2 = (h2){(_Float16)(-(float)rh), (_Float16)(-(float)rh)}; // {-rinv,-rinv}
        const h2 n1 = (h2){(_Float16)(-1.0f), (_Float16)(-1.0f)};

        h2 z = (h2){(_Float16)0.0f, (_Float16)0.0f};
        h2 a0 = z, a1 = z, a2 = z, a3 = z;
#pragma unroll
        for (int p = 0; p < NPAIR; p += 4) {
            h2 nw0, kn0, vn0, an0;
            asm("v_pk_mul_f16 %0, %1, %2" : "=&v"(nw0) : "v"(v[p + 0]), "v"(rn2));
            asm("v_pk_fma_f16 %0, %1, %2, %3" : "=&v"(kn0) : "v"(nw0), "v"(n1), "v"(kh[p + 0]));
            kh[p + 0] = kn0;
            asm("v_pk_fma_f16 %0, %1, %2, %3" : "=&v"(vn0) : "v"(nw0), "v"(v[p + 0]), "v"(v[p + 0]));
            v[p + 0] = vn0;
            asm("v_pk_add_f16 %0, %1, %2" : "=&v"(an0) : "v"(a0), "v"(v[p + 0]));
            a0 = an0;

            h2 nw1, kn1, vn1, an1;
            asm("v_pk_mul_f16 %0, %1, %2" : "=&v"(nw1) : "v"(v[p + 1]), "v"(rn2));
            asm("v_pk_fma_f16 %0, %1, %2, %3" : "=&v"(kn1) : "v"(nw1), "v"(n1), "v"(kh[p + 1]));
            kh[p + 1] = kn1;
            asm("v_pk_fma_f16 %0, %1, %2, %3" : "=&v"(vn1) : "v"(nw1), "v"(v[p + 1]), "v"(v[p + 1]));
            v[p + 1] = vn1;
            asm("v_pk_add_f16 %0, %1, %2" : "=&v"(an1) : "v"(a1), "v"(v[p + 1]));
            a1 = an1;

            h2 nw2, kn2, vn2, an2;
            asm("v_pk_mul_f16 %0, %1, %2" : "=&v"(nw2) : "v"(v[p + 2]), "v"(rn2));
            asm("v_pk_fma_f16 %0, %1, %2, %3" : "=&v"(kn2) : "v"(nw2), "v"(n1), "v"(kh[p + 2]));
            kh[p + 2] = kn2;
            asm("v_pk_fma_f16 %0, %1, %2, %3" : "=&v"(vn2) : "v"(nw2), "v"(v[p + 2]), "v"(v[p + 2]));
            v[p + 2] = vn2;
            asm("v_pk_add_f16 %0, %1, %2" : "=&v"(an2) : "v"(a2), "v"(v[p + 2]));
            a2 = an2;

            h2 nw3, kn3, vn3, an3;
            asm("v_pk_mul_f16 %0, %1, %2" : "=&v"(nw3) : "v"(v[p + 3]), "v"(rn2));
            asm("v_pk_fma_f16 %0, %1, %2, %3" : "=&v"(kn3) : "v"(nw3), "v"(n1), "v"(kh[p + 3]));
            kh[p + 3] = kn3;
            asm("v_pk_fma_f16 %0, %1, %2, %3" : "=&v"(vn3) : "v"(nw3), "v"(v[p + 3]), "v"(v[p + 3]));
            v[p + 3] = vn3;
            asm("v_pk_add_f16 %0, %1, %2" : "=&v"(an3) : "v"(a3), "v"(v[p + 3]));
            a3 = an3;
        }
        const h2 aa = (a0 + a1) + (a2 + a3);
        part = (float)aa.x + (float)aa.y;
        // single barrier per iteration: next write targets the other buffer;
        // this buffer is only re-written after the *next* barrier.
    }

    // ---- store khot (coalesced float4; pairs 2c, 2c+1 -> lanes xyzw) ----
#pragma unroll
    for (int c = 0; c < EPT / 4; ++c) {
        const int idx = c * (THREADS * 4) + t * 4;
        float4 o;
        o.x = (float)kh[2 * c + 0].x;
        o.y = (float)kh[2 * c + 0].y;
        o.z = (float)kh[2 * c + 1].x;
        o.w = (float)kh[2 * c + 1].y;
        *reinterpret_cast<float4*>(orow + idx) = o;
    }
}

extern "C" void kernel_launch(void* const* d_in, const int* in_sizes, int n_in,
                              void* d_out, int out_size, void* d_ws, size_t ws_size,
                              hipStream_t stream) {
    const float* scores = (const float*)d_in[0];
    const float* g = (const float*)d_in[1];
    float* out = (float*)d_out;
    (void)in_sizes; (void)n_in; (void)out_size; (void)d_ws; (void)ws_size;

    gumbel_subset_kernel<<<BROWS, THREADS, 0, stream>>>(scores, g, out);
}